// Round 1
// baseline (225.442 us; speedup 1.0000x reference)
//
#include <hip/hip_runtime.h>
#include <hip/hip_bf16.h>

#define UNITS 512
#define SEQ   4096
#define BATCH 32

typedef __attribute__((ext_vector_type(8))) __bf16 bf16x8;
typedef __attribute__((ext_vector_type(4))) __bf16 bf16x4;
typedef __attribute__((ext_vector_type(4))) float  f32x4;

// ---------------- K0: Uw [u][v] f32  ->  UwT [v][u] bf16 (B^T layout for MFMA) ----
__global__ void k_transpose(const float* __restrict__ Uw, __bf16* __restrict__ UwT) {
    __shared__ float tile[32][33];
    int k0 = blockIdx.x * 32, n0 = blockIdx.y * 32;
    int tx = threadIdx.x, ty = threadIdx.y;
#pragma unroll
    for (int i = 0; i < 4; i++) {
        int k = k0 + ty + i * 8;
        tile[ty + i * 8][tx] = Uw[k * UNITS + n0 + tx];
    }
    __syncthreads();
#pragma unroll
    for (int i = 0; i < 4; i++) {
        int n = n0 + ty + i * 8;
        UwT[n * UNITS + k0 + tx] = (__bf16)tile[tx][ty + i * 8];
    }
}

// ---------------- KA: ws_Ws[b][v] = s_prev[b,:] @ Ww[:,v] + Wb[v] + Ub[v] --------
__global__ void k_wsrow(const float* __restrict__ s_prev, const float* __restrict__ Ww,
                        const float* __restrict__ Wb, const float* __restrict__ Ub,
                        float* __restrict__ ws_Ws) {
    __shared__ float sp[UNITS];
    int b = blockIdx.x, t = threadIdx.x;
    sp[t] = s_prev[b * UNITS + t];
    sp[t + 256] = s_prev[b * UNITS + t + 256];
    __syncthreads();
    float a0 = Wb[t] + Ub[t];
    float a1 = Wb[t + 256] + Ub[t + 256];
#pragma unroll 8
    for (int u = 0; u < UNITS; u++) {
        float s = sp[u];
        a0 += s * Ww[u * UNITS + t];
        a1 += s * Ww[u * UNITS + t + 256];
    }
    ws_Ws[b * UNITS + t] = a0;
    ws_Ws[b * UNITS + t + 256] = a1;
}

// ---------------- KB: fused  tanh(Ws + hidden@Uw) @ Vw  ->  logit partials -------
// grid (2, 2048): x = n-half (256 cols), y = 64-row tile. block 512 thr = 8 waves.
#define BM 64
#define BN 256
#define BK 32
#define NSTEP (UNITS / BK)

__launch_bounds__(512)
__global__ void k_logits(const float* __restrict__ hidden, const __bf16* __restrict__ UwT,
                         const float* __restrict__ wsu, const float* __restrict__ Vw,
                         float* __restrict__ lpart) {
    __shared__ __bf16 Ab[2][BM * BK];   // [r][k] rows of 64 B
    __shared__ __bf16 Bb[2][BN * BK];   // [n][k] rows of 64 B
    __shared__ float  lred[BM][4];

    const int t = threadIdx.x;
    const int lane = t & 63, wv = t >> 6;
    const int wm = wv >> 2, wn = wv & 3;
    const int l15 = lane & 15, l4 = lane >> 4;
    const int gx = blockIdx.x;
    const int m0 = blockIdx.y * BM;
    const int b  = m0 >> 12;
    const int n0 = gx * BN;

    f32x4 acc[2][4];
#pragma unroll
    for (int i = 0; i < 2; i++)
#pragma unroll
        for (int j = 0; j < 4; j++) acc[i][j] = (f32x4){0.f, 0.f, 0.f, 0.f};

    auto stageA = [&](int buf, int kk) {
        int r = t >> 3, c4 = (t & 7) * 4;
        const float4 v = *(const float4*)(hidden + (size_t)(m0 + r) * UNITS + kk + c4);
        bf16x4 bv;
        bv[0] = (__bf16)v.x; bv[1] = (__bf16)v.y; bv[2] = (__bf16)v.z; bv[3] = (__bf16)v.w;
        *(bf16x4*)(&Ab[buf][r * BK + c4]) = bv;
    };
    auto stageB = [&](int buf, int kk) {
#pragma unroll
        for (int j = 0; j < 2; j++) {
            int idx = wv * 2 + j;          // 0..15, 16 rows each
            int nb = idx * 16;
            int n = nb + (lane >> 2);
            int ke = (lane & 3) * 8;
            const __bf16* gp = UwT + (size_t)(n0 + n) * UNITS + kk + ke;
            __builtin_amdgcn_global_load_lds(
                (const __attribute__((address_space(1))) void*)gp,
                (__attribute__((address_space(3))) void*)(&Bb[buf][nb * BK]),
                16, 0, 0);
        }
    };

    stageA(0, 0);
    stageB(0, 0);

#pragma unroll 2
    for (int step = 0; step < NSTEP; ++step) {
        __syncthreads();
        const int cur = step & 1;
        if (step + 1 < NSTEP) {
            stageA(cur ^ 1, (step + 1) * BK);
            stageB(cur ^ 1, (step + 1) * BK);
        }
        bf16x8 a[2], bfr[4];
#pragma unroll
        for (int fi = 0; fi < 2; fi++)
            a[fi] = *(const bf16x8*)(&Ab[cur][(wm * 32 + fi * 16 + l15) * BK + l4 * 8]);
#pragma unroll
        for (int fj = 0; fj < 4; fj++)
            bfr[fj] = *(const bf16x8*)(&Bb[cur][(wn * 64 + fj * 16 + l15) * BK + l4 * 8]);
#pragma unroll
        for (int fi = 0; fi < 2; fi++)
#pragma unroll
            for (int fj = 0; fj < 4; fj++)
                acc[fi][fj] = __builtin_amdgcn_mfma_f32_16x16x32_bf16(a[fi], bfr[fj], acc[fi][fj], 0, 0, 0);
    }

    // epilogue: tanh(acc + Ws+Ub) * Vw, reduce over this block's 256 cols
    float wsub[4], vww[4];
#pragma unroll
    for (int fj = 0; fj < 4; fj++) {
        int n = n0 + wn * 64 + fj * 16 + l15;
        wsub[fj] = wsu[b * UNITS + n];
        vww[fj]  = Vw[n];
    }
#pragma unroll
    for (int fi = 0; fi < 2; fi++) {
#pragma unroll
        for (int r = 0; r < 4; r++) {
            float p = 0.f;
#pragma unroll
            for (int fj = 0; fj < 4; fj++) {
                float x = acc[fi][fj][r] + wsub[fj];
                float e = __expf(2.f * x);
                p += vww[fj] * (1.f - 2.f / (e + 1.f));   // tanh(x)
            }
#pragma unroll
            for (int off = 1; off < 16; off <<= 1) p += __shfl_xor(p, off);
            if (l15 == 0) lred[wm * 32 + fi * 16 + l4 * 4 + r][wn] = p;
        }
    }
    __syncthreads();
    if (t < BM) {
        float s = lred[t][0] + lred[t][1] + lred[t][2] + lred[t][3];
        lpart[(size_t)(m0 + t) * 2 + gx] = s;
    }
}

// ---------------- KC: softmax over seq axis, write weights ----------------------
__global__ void k_softmax(const float* __restrict__ lpart, float* __restrict__ wout) {
    __shared__ float ebuf[SEQ];
    __shared__ float red[8];
    int b = blockIdx.x, t = threadIdx.x;
    int lane = t & 63, wv = t >> 6;
    float m = -1e30f;
#pragma unroll
    for (int i = 0; i < 16; i++) {
        int s = t + i * 256;
        size_t idx = ((size_t)b * SEQ + s) * 2;
        float l = lpart[idx] + lpart[idx + 1];
        ebuf[s] = l;
        m = fmaxf(m, l);
    }
#pragma unroll
    for (int off = 32; off >= 1; off >>= 1) m = fmaxf(m, __shfl_xor(m, off));
    if (lane == 0) red[wv] = m;
    __syncthreads();
    m = fmaxf(fmaxf(red[0], red[1]), fmaxf(red[2], red[3]));
    float zs = 0.f;
#pragma unroll
    for (int i = 0; i < 16; i++) {
        int s = t + i * 256;
        float e = __expf(ebuf[s] - m);
        ebuf[s] = e;
        zs += e;
    }
#pragma unroll
    for (int off = 32; off >= 1; off >>= 1) zs += __shfl_xor(zs, off);
    __syncthreads();
    if (lane == 0) red[wv] = zs;
    __syncthreads();
    float inv = 1.f / (red[0] + red[1] + red[2] + red[3]);
#pragma unroll
    for (int i = 0; i < 16; i++) {
        int s = t + i * 256;
        wout[(size_t)b * SEQ + s] = ebuf[s] * inv;
    }
}

// ---------------- KD: context partials over 128-seq chunks ----------------------
__global__ void k_ctxpart(const float* __restrict__ hidden, const float* __restrict__ wout,
                          float* __restrict__ part) {
    int b = blockIdx.y, c = blockIdx.x, t = threadIdx.x;
    const float* w = wout + (size_t)b * SEQ + c * 128;
    const float* h = hidden + ((size_t)b * SEQ + c * 128) * UNITS;
    float2 acc = make_float2(0.f, 0.f);
#pragma unroll 4
    for (int s = 0; s < 128; s++) {
        float ww = w[s];
        float2 v = ((const float2*)(h + (size_t)s * UNITS))[t];
        acc.x += ww * v.x;
        acc.y += ww * v.y;
    }
    ((float2*)(part + ((size_t)(b * 32 + c)) * UNITS))[t] = acc;
}

// ---------------- KE: reduce partials -> context --------------------------------
__global__ void k_ctxreduce(const float* __restrict__ part, float* __restrict__ ctx) {
    int b = blockIdx.x, t = threadIdx.x;   // 512 threads, one u each
    float s = 0.f;
#pragma unroll
    for (int c = 0; c < 32; c++) s += part[((size_t)(b * 32 + c)) * UNITS + t];
    ctx[(size_t)b * UNITS + t] = s;
}

extern "C" void kernel_launch(void* const* d_in, const int* in_sizes, int n_in,
                              void* d_out, int out_size, void* d_ws, size_t ws_size,
                              hipStream_t stream) {
    const float* s_prev = (const float*)d_in[0];
    const float* hidden = (const float*)d_in[1];
    const float* Ww     = (const float*)d_in[2];
    const float* Wb     = (const float*)d_in[3];
    const float* Uw     = (const float*)d_in[4];
    const float* Ub     = (const float*)d_in[5];
    const float* Vw     = (const float*)d_in[6];
    // d_in[7] = Vb: constant shift, cancels in softmax; weights/context unaffected.

    float* out  = (float*)d_out;
    float* ctx  = out;                    // [32, 512]
    float* wout = out + BATCH * UNITS;    // [32, 4096, 1]

    float* wsf   = (float*)d_ws;
    float* ws_Ws = wsf;                                  // 16384 f32
    float* ws_lp = ws_Ws + BATCH * UNITS;                // 262144 f32 (logit partials x2)
    float* ws_cp = ws_lp + (size_t)BATCH * SEQ * 2;      // 524288 f32 (ctx partials)
    __bf16* UwT  = (__bf16*)(ws_cp + (size_t)BATCH * 32 * UNITS);  // 512 KB bf16

    k_transpose<<<dim3(16, 16), dim3(32, 8), 0, stream>>>(Uw, UwT);
    k_wsrow<<<dim3(32), dim3(256), 0, stream>>>(s_prev, Ww, Wb, Ub, ws_Ws);
    k_logits<<<dim3(2, 2048), dim3(512), 0, stream>>>(hidden, UwT, ws_Ws, Vw, ws_lp);
    k_softmax<<<dim3(32), dim3(256), 0, stream>>>(ws_lp, wout);
    k_ctxpart<<<dim3(32, 32), dim3(256), 0, stream>>>(hidden, wout, ws_cp);
    k_ctxreduce<<<dim3(32), dim3(512), 0, stream>>>(ws_cp, ctx);
}

// Round 2
// 209.296 us; speedup vs baseline: 1.0771x; 1.0771x over previous
//
#include <hip/hip_runtime.h>
#include <hip/hip_bf16.h>

#define UNITS 512
#define SEQ   4096
#define BATCH 32

typedef __attribute__((ext_vector_type(8))) __bf16 bf16x8;
typedef __attribute__((ext_vector_type(4))) float  f32x4;

// LDS bank-conflict swizzle: phys = logical ^ (((logical>>6)&7)<<4).
// Row stride is 64B, so rows alias 8-way without this; the XOR spreads each
// 16-row x 64B fragment region across all 32 banks exactly 2-way (free).
__device__ __forceinline__ int swz(int l) { return l ^ (((l >> 6) & 7) << 4); }

// ---------------- K0: Uw [k][n] f32 -> UwTt tiled + pre-swizzled bf16 ----------
// UwTt = 32 tiles of 16KB, tile T = kstep*2 + half. Within a tile, the byte at
// offset swz(n_local*64 + c*16) holds B-row n_local, k-chunk c (8 bf16).
// k_logits then stages a tile with LINEAR contiguous global_load_lds and reads
// with swz() -> conflict-free, zero VALU on the B path.
__global__ void k_bprep(const float* __restrict__ Uw, __bf16* __restrict__ UwTt) {
    const int c     = blockIdx.x;   // k-chunk within step (0..3), 8 elems each
    const int half  = blockIdx.y;   // n half (0..1)
    const int kstep = blockIdx.z;   // 0..15
    const int t     = threadIdx.x;  // n within half (0..255)
    const int n = half * 256 + t;
    bf16x8 o;
#pragma unroll
    for (int j = 0; j < 8; j++)
        o[j] = (__bf16)Uw[(size_t)(kstep * 32 + c * 8 + j) * UNITS + n];
    const int tile = kstep * 2 + half;
    char* dst = (char*)UwTt + (size_t)tile * 16384 + swz(t * 64 + c * 16);
    *(bf16x8*)dst = o;
}

// ---------------- KA: ws_Ws[b][v] = s_prev[b,:] @ Ww[:,v] + Wb[v] + Ub[v] --------
__global__ void k_wsrow(const float* __restrict__ s_prev, const float* __restrict__ Ww,
                        const float* __restrict__ Wb, const float* __restrict__ Ub,
                        float* __restrict__ ws_Ws) {
    __shared__ float sp[UNITS];
    int b = blockIdx.x, t = threadIdx.x;
    sp[t] = s_prev[b * UNITS + t];
    sp[t + 256] = s_prev[b * UNITS + t + 256];
    __syncthreads();
    float a0 = Wb[t] + Ub[t];
    float a1 = Wb[t + 256] + Ub[t + 256];
#pragma unroll 8
    for (int u = 0; u < UNITS; u++) {
        float s = sp[u];
        a0 += s * Ww[u * UNITS + t];
        a1 += s * Ww[u * UNITS + t + 256];
    }
    ws_Ws[b * UNITS + t] = a0;
    ws_Ws[b * UNITS + t + 256] = a1;
}

// ---------------- KB: fused  tanh(Ws + hidden@Uw) @ Vw  ->  logit partials -------
// grid (2, 1024): x = n-half (256 cols), y = 128-row tile. 512 thr = 8 waves.
// Wave tile 64x64 (4x4 fragments of 16x16x32) -> 16 MFMA per wave-step vs
// 8 conflict-free ds_read_b128.
#define BM 128
#define BN 256
#define BK 32
#define NSTEP (UNITS / BK)

__launch_bounds__(512, 4)
__global__ void k_logits(const float* __restrict__ hidden, const __bf16* __restrict__ UwTt,
                         const float* __restrict__ wsu, const float* __restrict__ Vw,
                         float* __restrict__ lpart) {
    __shared__ __bf16 Ab[2][BM * BK];   // 8KB per buf, swizzled
    __shared__ __bf16 Bb[2][BN * BK];   // 16KB per buf, swizzled (pre-swizzled src)
    __shared__ float  lred[BM][4];

    const int t = threadIdx.x;
    const int lane = t & 63, wv = t >> 6;
    const int wm = wv >> 2, wn = wv & 3;          // 2 x 4 wave grid
    const int l15 = lane & 15, l4 = lane >> 4;    // l4 in 0..3
    const int gx = blockIdx.x;
    const int m0 = blockIdx.y * BM;
    const int b  = m0 >> 12;                      // 4096 rows per batch

    f32x4 acc[4][4];
#pragma unroll
    for (int i = 0; i < 4; i++)
#pragma unroll
        for (int j = 0; j < 4; j++) acc[i][j] = (f32x4){0.f, 0.f, 0.f, 0.f};

    // ---- A staging: 512 thr x 8 f32 = 128 rows x 32 k per step ----
    const int sr = t >> 2;                  // stage row 0..127
    const int sc = t & 3;                   // 8-elem chunk 0..3
    const float* aRow = hidden + (size_t)(m0 + sr) * UNITS + sc * 8;
    const int aoffW = swz(sr * 64 + sc * 16);

    // ---- fragment read offsets (swizzled, conflict-free) ----
    int aoffR[4], boffR[4];
#pragma unroll
    for (int f = 0; f < 4; f++) {
        aoffR[f] = swz((wm * 64 + f * 16 + l15) * 64 + l4 * 16);
        boffR[f] = swz((wn * 64 + f * 16 + l15) * 64 + l4 * 16);
    }

    auto stageA = [&](int buf, int kk) {
        float4 v0 = *(const float4*)(aRow + kk);
        float4 v1 = *(const float4*)(aRow + kk + 4);
        bf16x8 o;
        o[0] = (__bf16)v0.x; o[1] = (__bf16)v0.y; o[2] = (__bf16)v0.z; o[3] = (__bf16)v0.w;
        o[4] = (__bf16)v1.x; o[5] = (__bf16)v1.y; o[6] = (__bf16)v1.z; o[7] = (__bf16)v1.w;
        *(bf16x8*)((char*)(&Ab[buf][0]) + aoffW) = o;
    };
    auto stageB = [&](int buf, int step) {
        // tile is stored pre-swizzled: straight contiguous 2KB copy per wave
        const char* src = (const char*)UwTt + (size_t)(step * 2 + gx) * 16384
                        + wv * 2048 + lane * 16;
        char* dst = (char*)(&Bb[buf][0]) + wv * 2048;
        __builtin_amdgcn_global_load_lds(
            (const __attribute__((address_space(1))) void*)src,
            (__attribute__((address_space(3))) void*)dst, 16, 0, 0);
        __builtin_amdgcn_global_load_lds(
            (const __attribute__((address_space(1))) void*)(src + 1024),
            (__attribute__((address_space(3))) void*)(dst + 1024), 16, 0, 0);
    };

    stageA(0, 0);
    stageB(0, 0);

#pragma unroll 2
    for (int step = 0; step < NSTEP; ++step) {
        __syncthreads();
        const int cur = step & 1;
        if (step + 1 < NSTEP) {
            stageA(cur ^ 1, (step + 1) * BK);
            stageB(cur ^ 1, step + 1);
        }
        bf16x8 a[4], bq[4];
#pragma unroll
        for (int fi = 0; fi < 4; fi++)
            a[fi] = *(const bf16x8*)((char*)(&Ab[cur][0]) + aoffR[fi]);
#pragma unroll
        for (int fj = 0; fj < 4; fj++)
            bq[fj] = *(const bf16x8*)((char*)(&Bb[cur][0]) + boffR[fj]);
#pragma unroll
        for (int fi = 0; fi < 4; fi++)
#pragma unroll
            for (int fj = 0; fj < 4; fj++)
                acc[fi][fj] = __builtin_amdgcn_mfma_f32_16x16x32_bf16(a[fi], bq[fj], acc[fi][fj], 0, 0, 0);
    }

    // epilogue: tanh(acc + Ws+Ub) * Vw, reduce over this block's 256 cols
    float wsub[4], vww[4];
#pragma unroll
    for (int fj = 0; fj < 4; fj++) {
        int n = gx * BN + wn * 64 + fj * 16 + l15;
        wsub[fj] = wsu[b * UNITS + n];
        vww[fj]  = Vw[n];
    }
#pragma unroll
    for (int fi = 0; fi < 4; fi++) {
#pragma unroll
        for (int r = 0; r < 4; r++) {
            float p = 0.f;
#pragma unroll
            for (int fj = 0; fj < 4; fj++) {
                float x = acc[fi][fj][r] + wsub[fj];
                float e = __expf(2.f * x);
                p += vww[fj] * (1.f - 2.f / (e + 1.f));   // tanh(x)
            }
#pragma unroll
            for (int off = 1; off < 16; off <<= 1) p += __shfl_xor(p, off);
            if (l15 == 0) lred[wm * 64 + fi * 16 + l4 * 4 + r][wn] = p;
        }
    }
    __syncthreads();
    if (t < BM) {
        float s = lred[t][0] + lred[t][1] + lred[t][2] + lred[t][3];
        lpart[(size_t)(m0 + t) * 2 + gx] = s;
    }
}

// ---------------- KC: softmax over seq axis, write weights ----------------------
__global__ void k_softmax(const float* __restrict__ lpart, float* __restrict__ wout) {
    __shared__ float ebuf[SEQ];
    __shared__ float red[8];
    int b = blockIdx.x, t = threadIdx.x;
    int lane = t & 63, wv = t >> 6;
    float m = -1e30f;
#pragma unroll
    for (int i = 0; i < 16; i++) {
        int s = t + i * 256;
        size_t idx = ((size_t)b * SEQ + s) * 2;
        float l = lpart[idx] + lpart[idx + 1];
        ebuf[s] = l;
        m = fmaxf(m, l);
    }
#pragma unroll
    for (int off = 32; off >= 1; off >>= 1) m = fmaxf(m, __shfl_xor(m, off));
    if (lane == 0) red[wv] = m;
    __syncthreads();
    m = fmaxf(fmaxf(red[0], red[1]), fmaxf(red[2], red[3]));
    float zs = 0.f;
#pragma unroll
    for (int i = 0; i < 16; i++) {
        int s = t + i * 256;
        float e = __expf(ebuf[s] - m);
        ebuf[s] = e;
        zs += e;
    }
#pragma unroll
    for (int off = 32; off >= 1; off >>= 1) zs += __shfl_xor(zs, off);
    __syncthreads();
    if (lane == 0) red[wv] = zs;
    __syncthreads();
    float inv = 1.f / (red[0] + red[1] + red[2] + red[3]);
#pragma unroll
    for (int i = 0; i < 16; i++) {
        int s = t + i * 256;
        wout[(size_t)b * SEQ + s] = ebuf[s] * inv;
    }
}

// ---------------- KD: context partials over 128-seq chunks ----------------------
__global__ void k_ctxpart(const float* __restrict__ hidden, const float* __restrict__ wout,
                          float* __restrict__ part) {
    int b = blockIdx.y, c = blockIdx.x, t = threadIdx.x;
    const float* w = wout + (size_t)b * SEQ + c * 128;
    const float* h = hidden + ((size_t)b * SEQ + c * 128) * UNITS;
    float2 acc = make_float2(0.f, 0.f);
#pragma unroll 4
    for (int s = 0; s < 128; s++) {
        float ww = w[s];
        float2 v = ((const float2*)(h + (size_t)s * UNITS))[t];
        acc.x += ww * v.x;
        acc.y += ww * v.y;
    }
    ((float2*)(part + ((size_t)(b * 32 + c)) * UNITS))[t] = acc;
}

// ---------------- KE: reduce partials -> context --------------------------------
__global__ void k_ctxreduce(const float* __restrict__ part, float* __restrict__ ctx) {
    int b = blockIdx.x, t = threadIdx.x;   // 512 threads, one u each
    float s = 0.f;
#pragma unroll
    for (int c = 0; c < 32; c++) s += part[((size_t)(b * 32 + c)) * UNITS + t];
    ctx[(size_t)b * UNITS + t] = s;
}

extern "C" void kernel_launch(void* const* d_in, const int* in_sizes, int n_in,
                              void* d_out, int out_size, void* d_ws, size_t ws_size,
                              hipStream_t stream) {
    const float* s_prev = (const float*)d_in[0];
    const float* hidden = (const float*)d_in[1];
    const float* Ww     = (const float*)d_in[2];
    const float* Wb     = (const float*)d_in[3];
    const float* Uw     = (const float*)d_in[4];
    const float* Ub     = (const float*)d_in[5];
    const float* Vw     = (const float*)d_in[6];
    // d_in[7] = Vb: constant shift, cancels in softmax.

    float* out  = (float*)d_out;
    float* ctx  = out;                    // [32, 512]
    float* wout = out + BATCH * UNITS;    // [32, 4096, 1]

    float* wsf   = (float*)d_ws;
    float* ws_Ws = wsf;                                  // 16384 f32
    float* ws_lp = ws_Ws + BATCH * UNITS;                // 262144 f32 (logit partials x2)
    float* ws_cp = ws_lp + (size_t)BATCH * SEQ * 2;      // 524288 f32 (ctx partials)
    __bf16* UwTt = (__bf16*)(ws_cp + (size_t)BATCH * 32 * UNITS);  // 512 KB bf16, tiled+swizzled

    k_bprep<<<dim3(4, 2, 16), dim3(256), 0, stream>>>(Uw, UwTt);
    k_wsrow<<<dim3(32), dim3(256), 0, stream>>>(s_prev, Ww, Wb, Ub, ws_Ws);
    k_logits<<<dim3(2, 1024), dim3(512), 0, stream>>>(hidden, UwTt, ws_Ws, Vw, ws_lp);
    k_softmax<<<dim3(32), dim3(256), 0, stream>>>(ws_lp, wout);
    k_ctxpart<<<dim3(32, 32), dim3(256), 0, stream>>>(hidden, wout, ws_cp);
    k_ctxreduce<<<dim3(32), dim3(512), 0, stream>>>(ws_cp, ctx);
}